// Round 1
// baseline (533.479 us; speedup 1.0000x reference)
//
#include <hip/hip_runtime.h>
#include <hip/hip_bf16.h>
#include <math.h>

#define BB 2
#define MM 8192
#define NN (BB * MM)

// ws layout:
//   [0,64)            : 6 float accumulators (wd, w, pos, neg, sm, di)
//   [64, 64+4N)       : rank per point (int)
//   [65600, +16*4*N)  : knn indices (int, 16 per point)
//   [1114176, +16*N)  : packed float4 (x,y,z,|c|^2)
#define ACC_OFF  0
#define RANK_OFF 64
#define IDX_OFF  65600
#define PK_OFF   1114176

__global__ void prep_kernel(const float* __restrict__ coords, float4* __restrict__ pk) {
    int i = blockIdx.x * blockDim.x + threadIdx.x;
    if (i < NN) {
        float x = coords[3 * i], y = coords[3 * i + 1], z = coords[3 * i + 2];
        // MUST match dot ordering in knn_kernel so self-distance is exactly 0.
        float sq = fmaf(x, x, fmaf(y, y, z * z));
        pk[i] = make_float4(x, y, z, sq);
    }
}

// 256 blocks x 256 threads. Block handles 64 queries (one per lane);
// wave w scans candidates [w*2048, (w+1)*2048) of the query's cloud.
__global__ __launch_bounds__(256) void knn_kernel(const float* __restrict__ scores,
                                                  const float4* __restrict__ pk,
                                                  int* __restrict__ out_idx,
                                                  int* __restrict__ out_rank) {
    __shared__ unsigned lds_k[4][64][16];
    __shared__ int lds_r[4][64];

    const int tid  = threadIdx.x;
    const int lane = tid & 63;
    const int wv   = __builtin_amdgcn_readfirstlane(tid >> 6);  // wave id, uniform (SGPR)
    const int qbase = blockIdx.x * 64;
    const int cbase = (qbase >> 13) << 13;  // cloud base, uniform expression -> scalar loads
    const int q = qbase + lane;

    float4 p = pk[q];
    float  s = scores[q];

    // top-16 as packed keys: (order-preserving d2 bits & ~0x1FFF) | local_j  (M=8192 -> 13 bits)
    unsigned slot[16];
#pragma unroll
    for (int k = 0; k < 16; ++k) slot[k] = 0xFFFF0000u + (unsigned)k;  // distinct sentinels
    unsigned thr = 0xFFFF000Fu;  // current max of slots
    int rank = 0;

    const int j0 = wv * 2048;
    for (int jj = 0; jj < 2048; ++jj) {
        const int j = j0 + jj;                       // wave-uniform
        const float4 c = pk[cbase + j];              // s_load_dwordx4
        const float  sc = scores[cbase + j];         // s_load_dword
        float dot = fmaf(p.x, c.x, fmaf(p.y, c.y, p.z * c.z));
        float d2  = fmaf(-2.0f, dot, p.w + c.w);     // == 0 exactly for j == q-local
        rank += (sc < s) ? 1 : 0;
        unsigned u = __float_as_uint(d2);
        unsigned ord = u ^ (0x80000000u | (unsigned)((int)u >> 31));  // total order incl. negatives
        unsigned key = (ord & 0xFFFFE000u) | (unsigned)j;
        if (key < thr) {  // exec-masked branch: wave pays only when some lane inserts
#pragma unroll
            for (int k = 0; k < 16; ++k) slot[k] = (slot[k] == thr) ? key : slot[k];
            unsigned m = slot[0];
#pragma unroll
            for (int k = 1; k < 16; ++k) m = max(m, slot[k]);
            thr = m;
        }
    }

    // Batcher odd-even mergesort of 16 keys (ascending) -> (d2, idx) lexicographic
#pragma unroll
    for (int p2 = 1; p2 < 16; p2 <<= 1) {
#pragma unroll
        for (int k2 = p2; k2 >= 1; k2 >>= 1) {
#pragma unroll
            for (int j2 = k2 % p2; j2 + k2 < 16; j2 += 2 * k2) {
#pragma unroll
                for (int i2 = 0; i2 < k2; ++i2) {
                    if (i2 + j2 + k2 < 16) {
                        if (((i2 + j2) / (2 * p2)) == ((i2 + j2 + k2) / (2 * p2))) {
                            unsigned a = slot[i2 + j2], b = slot[i2 + j2 + k2];
                            slot[i2 + j2]      = min(a, b);
                            slot[i2 + j2 + k2] = max(a, b);
                        }
                    }
                }
            }
        }
    }

#pragma unroll
    for (int k = 0; k < 16; ++k) lds_k[wv][lane][k] = slot[k];
    lds_r[wv][lane] = rank;
    __syncthreads();

    // wave 0: 4-way merge of sorted 16-lists per query (keys globally unique)
    if (tid < 64) {
        const int l = tid;
        unsigned h0 = 0, h1 = 0, h2 = 0, h3 = 0;
        unsigned v0 = lds_k[0][l][0], v1 = lds_k[1][l][0];
        unsigned v2 = lds_k[2][l][0], v3 = lds_k[3][l][0];
        const int obase = (qbase + l) * 16;
#pragma unroll
        for (int o = 0; o < 16; ++o) {
            unsigned m = min(min(v0, v1), min(v2, v3));
            out_idx[obase + o] = (int)(m & 0x1FFFu) + cbase;
            if (v0 == m)      { h0++; v0 = (h0 < 16) ? lds_k[0][l][h0] : 0xFFFFFFFFu; }
            else if (v1 == m) { h1++; v1 = (h1 < 16) ? lds_k[1][l][h1] : 0xFFFFFFFFu; }
            else if (v2 == m) { h2++; v2 = (h2 < 16) ? lds_k[2][l][h2] : 0xFFFFFFFFu; }
            else              { h3++; v3 = (h3 < 16) ? lds_k[3][l][h3] : 0xFFFFFFFFu; }
        }
        out_rank[qbase + l] = lds_r[0][l] + lds_r[1][l] + lds_r[2][l] + lds_r[3][l];
    }
}

__global__ __launch_bounds__(256) void loss_kernel(const float* __restrict__ scores,
                                                   const float* __restrict__ coords,
                                                   const int* __restrict__ knn,
                                                   const int* __restrict__ rank,
                                                   float* __restrict__ acc) {
    const int q = blockIdx.x * 256 + threadIdx.x;
    const float s = scores[q];
    const float cx = coords[3 * q], cy = coords[3 * q + 1], cz = coords[3 * q + 2];
    float a_wd = 0.f, a_w = 0.f, a_pos = 0.f, a_neg = 0.f, nsum = 0.f;
#pragma unroll
    for (int k = 0; k < 8; ++k) {
        int nb = knn[q * 16 + k];
        float sn = scores[nb];
        float nx = coords[3 * nb], ny = coords[3 * nb + 1], nz = coords[3 * nb + 2];
        float dx = cx - nx, dy = cy - ny, dz = cz - nz;
        float d = sqrtf(dx * dx + dy * dy + dz * dz);
        float w = expf(-10.0f * d);                 // exp(-d / 0.1)
        float diff = fabsf(s - sn);
        a_wd += w * diff * diff;
        a_w  += w;
        float sim = 1.0f - diff;
        float sg = 1.0f / (1.0f + expf(-2.0f * sim));  // sigmoid(sim / 0.5)
        a_pos += logf(sg + 1e-8f);
        nsum += sn;
    }
#pragma unroll
    for (int k = 8; k < 16; ++k) {
        int nb = knn[q * 16 + k];
        float diff = fabsf(s - scores[nb]);
        float sim = 1.0f - diff;
        float sg = 1.0f / (1.0f + expf(-2.0f * sim));
        a_neg += logf(1.0f - sg + 1e-8f);
    }
    float t1 = s - nsum * 0.125f;
    float a_sm = t1 * t1;
    float t2 = s - (float)rank[q] * (1.0f / 8191.0f);  // linspace(0,1,M)[rank]
    float a_di = t2 * t2;

#pragma unroll
    for (int off = 32; off >= 1; off >>= 1) {
        a_wd  += __shfl_down(a_wd, off);
        a_w   += __shfl_down(a_w, off);
        a_pos += __shfl_down(a_pos, off);
        a_neg += __shfl_down(a_neg, off);
        a_sm  += __shfl_down(a_sm, off);
        a_di  += __shfl_down(a_di, off);
    }
    if ((threadIdx.x & 63) == 0) {
        atomicAdd(&acc[0], a_wd);
        atomicAdd(&acc[1], a_w);
        atomicAdd(&acc[2], a_pos);
        atomicAdd(&acc[3], a_neg);
        atomicAdd(&acc[4], a_sm);
        atomicAdd(&acc[5], a_di);
    }
}

__global__ void fin_kernel(const float* __restrict__ acc, float* __restrict__ out) {
    if (threadIdx.x == 0) {
        float l_loc = acc[0] / fmaxf(acc[1], 1e-8f);
        float l_pos = -acc[2] / (float)(NN * 8);
        float l_neg = -acc[3] / (float)(NN * 8);
        float l_sm  = acc[4] / (float)NN;
        float l_di  = acc[5] / (float)NN;
        out[0] = l_loc + 0.5f * (l_pos + l_neg) + 0.3f * l_di + 0.2f * l_sm;
    }
}

extern "C" void kernel_launch(void* const* d_in, const int* in_sizes, int n_in,
                              void* d_out, int out_size, void* d_ws, size_t ws_size,
                              hipStream_t stream) {
    const float* scores = (const float*)d_in[0];
    const float* coords = (const float*)d_in[1];
    (void)in_sizes; (void)n_in; (void)out_size; (void)ws_size;

    char* ws = (char*)d_ws;
    float*  acc  = (float*)(ws + ACC_OFF);
    int*    rank = (int*)(ws + RANK_OFF);
    int*    knn  = (int*)(ws + IDX_OFF);
    float4* pk   = (float4*)(ws + PK_OFF);
    float*  out  = (float*)d_out;

    hipMemsetAsync(acc, 0, 64, stream);
    prep_kernel<<<64, 256, 0, stream>>>(coords, pk);
    knn_kernel<<<256, 256, 0, stream>>>(scores, pk, knn, rank);
    loss_kernel<<<64, 256, 0, stream>>>(scores, coords, knn, rank, acc);
    fin_kernel<<<1, 64, 0, stream>>>(acc, out);
}